// Round 1
// baseline (7415.912 us; speedup 1.0000x reference)
//
#include <hip/hip_runtime.h>
#include <hip/hip_bf16.h>

// GCN 2-layer forward, f32 baseline.
// x[50000,1433] @ W1[1433,256] -> scatter-norm-add -> +b1, relu -> @W2[256,7]
// -> scatter-norm-add -> +b2.

#define N_NODES_   50000
#define N_EDGES_   1600000
#define N_FEAT_    1433
#define HIDDEN_    256
#define N_CLASSES_ 7

// ---------------- degree / norm ----------------
__global__ void deg_kernel(const int* __restrict__ dst, int* __restrict__ deg) {
    int i = blockIdx.x * blockDim.x + threadIdx.x;
    if (i < N_EDGES_) atomicAdd(&deg[dst[i]], 1);
}

__global__ void dinv_kernel(const int* __restrict__ deg, float* __restrict__ dinv) {
    int i = blockIdx.x * blockDim.x + threadIdx.x;
    if (i < N_NODES_) dinv[i] = rsqrtf((float)(deg[i] + 1));  // +1 self-loop
}

// ---------------- GEMM1: h1 = x @ W1  (f32, 64x64 tile, 4x4 microtile) ----------------
#define TM 64
#define TN 64
#define TK 16
__global__ __launch_bounds__(256) void gemm1_kernel(const float* __restrict__ A,
                                                    const float* __restrict__ B,
                                                    float* __restrict__ C) {
    __shared__ float As[TK][TM + 4];  // +4 pad: keeps float4 alignment, breaks pow2 stride
    __shared__ float Bs[TK][TN + 4];

    const int tid  = threadIdx.x;          // 0..255
    const int row0 = blockIdx.x * TM;
    const int col0 = blockIdx.y * TN;
    const int tr   = tid >> 4;             // 0..15
    const int tc   = tid & 15;             // 0..15

    float acc[4][4] = {};

    for (int k0 = 0; k0 < N_FEAT_; k0 += TK) {
        // A tile: 64 rows x 16 k (store transposed As[k][m])
        #pragma unroll
        for (int i = 0; i < 4; i++) {
            int idx = tid + i * 256;       // 0..1023
            int m = idx >> 4;
            int k = idx & 15;
            int gm = row0 + m, gk = k0 + k;
            float v = 0.f;
            if (gm < N_NODES_ && gk < N_FEAT_) v = A[(long)gm * N_FEAT_ + gk];
            As[k][m] = v;
        }
        // B tile: 16 k x 64 n
        #pragma unroll
        for (int i = 0; i < 4; i++) {
            int idx = tid + i * 256;
            int k = idx >> 6;
            int n = idx & 63;
            int gk = k0 + k;
            float v = 0.f;
            if (gk < N_FEAT_) v = B[(long)gk * HIDDEN_ + col0 + n];
            Bs[k][n] = v;
        }
        __syncthreads();

        #pragma unroll
        for (int k = 0; k < TK; k++) {
            float4 a4 = *(const float4*)&As[k][tr * 4];
            float4 b4 = *(const float4*)&Bs[k][tc * 4];
            float a[4] = {a4.x, a4.y, a4.z, a4.w};
            float b[4] = {b4.x, b4.y, b4.z, b4.w};
            #pragma unroll
            for (int i = 0; i < 4; i++)
                #pragma unroll
                for (int j = 0; j < 4; j++)
                    acc[i][j] += a[i] * b[j];
        }
        __syncthreads();
    }

    #pragma unroll
    for (int i = 0; i < 4; i++) {
        int gm = row0 + tr * 4 + i;
        if (gm < N_NODES_) {
            float4 v = make_float4(acc[i][0], acc[i][1], acc[i][2], acc[i][3]);
            *(float4*)&C[(long)gm * HIDDEN_ + col0 + tc * 4] = v;
        }
    }
}

// ---------------- scatter1: agg1[dst] += h1[src] * dinv[src]*dinv[dst] ----------------
// One 64-lane slot per item (edge or self-loop); each lane handles 4 features.
__global__ void scatter1_kernel(const int* __restrict__ src, const int* __restrict__ dst,
                                const float* __restrict__ dinv,
                                const float* __restrict__ h1, float* __restrict__ agg1) {
    long gid = (long)blockIdx.x * blockDim.x + threadIdx.x;
    long item = gid >> 6;
    int lane = (int)(gid & 63);
    if (item >= (long)N_EDGES_ + N_NODES_) return;
    int s, d;
    float norm;
    if (item < N_EDGES_) {
        s = src[item]; d = dst[item];
        norm = dinv[s] * dinv[d];
    } else {
        s = d = (int)(item - N_EDGES_);
        float di = dinv[s];
        norm = di * di;
    }
    float4 v = ((const float4*)(h1 + (long)s * HIDDEN_))[lane];
    float* op = agg1 + (long)d * HIDDEN_ + lane * 4;
    atomicAdd(op + 0, v.x * norm);
    atomicAdd(op + 1, v.y * norm);
    atomicAdd(op + 2, v.z * norm);
    atomicAdd(op + 3, v.w * norm);
}

// ---------------- GEMM2 fused: h2 = relu(agg1 + b1) @ W2 ----------------
// One wave per node; lane holds 4 of 256 features; 7-way shuffle reduce.
__global__ __launch_bounds__(256) void gemm2_kernel(const float* __restrict__ agg1,
                                                    const float* __restrict__ b1,
                                                    const float* __restrict__ W2,
                                                    float* __restrict__ h2) {
    __shared__ float w2s[HIDDEN_ * N_CLASSES_];
    __shared__ float b1s[HIDDEN_];
    int tid = threadIdx.x;
    for (int i = tid; i < HIDDEN_ * N_CLASSES_; i += 256) w2s[i] = W2[i];
    for (int i = tid; i < HIDDEN_; i += 256) b1s[i] = b1[i];
    __syncthreads();

    int wave = tid >> 6;
    int lane = tid & 63;
    int node = blockIdx.x * 4 + wave;
    if (node >= N_NODES_) return;

    float4 v = ((const float4*)(agg1 + (long)node * HIDDEN_))[lane];
    float xv[4];
    xv[0] = fmaxf(v.x + b1s[lane * 4 + 0], 0.f);
    xv[1] = fmaxf(v.y + b1s[lane * 4 + 1], 0.f);
    xv[2] = fmaxf(v.z + b1s[lane * 4 + 2], 0.f);
    xv[3] = fmaxf(v.w + b1s[lane * 4 + 3], 0.f);

    float p[N_CLASSES_];
    #pragma unroll
    for (int c = 0; c < N_CLASSES_; c++) {
        float acc = 0.f;
        #pragma unroll
        for (int i = 0; i < 4; i++)
            acc += xv[i] * w2s[(lane * 4 + i) * N_CLASSES_ + c];
        p[c] = acc;
    }
    #pragma unroll
    for (int off = 32; off > 0; off >>= 1)
        #pragma unroll
        for (int c = 0; c < N_CLASSES_; c++)
            p[c] += __shfl_down(p[c], off, 64);
    if (lane == 0) {
        #pragma unroll
        for (int c = 0; c < N_CLASSES_; c++)
            h2[(long)node * N_CLASSES_ + c] = p[c];
    }
}

// ---------------- scatter2: out[dst] += h2[src] * norm ----------------
__global__ void scatter2_kernel(const int* __restrict__ src, const int* __restrict__ dst,
                                const float* __restrict__ dinv,
                                const float* __restrict__ h2, float* __restrict__ out) {
    long item = (long)blockIdx.x * blockDim.x + threadIdx.x;
    if (item >= (long)N_EDGES_ + N_NODES_) return;
    int s, d;
    float norm;
    if (item < N_EDGES_) {
        s = src[item]; d = dst[item];
        norm = dinv[s] * dinv[d];
    } else {
        s = d = (int)(item - N_EDGES_);
        float di = dinv[s];
        norm = di * di;
    }
    const float* hp = h2 + (long)s * N_CLASSES_;
    float* op = out + (long)d * N_CLASSES_;
    #pragma unroll
    for (int c = 0; c < N_CLASSES_; c++)
        atomicAdd(op + c, hp[c] * norm);
}

__global__ void bias2_kernel(float* __restrict__ out, const float* __restrict__ b2) {
    int i = blockIdx.x * blockDim.x + threadIdx.x;
    if (i < N_NODES_ * N_CLASSES_) out[i] += b2[i % N_CLASSES_];
}

extern "C" void kernel_launch(void* const* d_in, const int* in_sizes, int n_in,
                              void* d_out, int out_size, void* d_ws, size_t ws_size,
                              hipStream_t stream) {
    const float* x   = (const float*)d_in[0];
    const int*   ei  = (const int*)d_in[1];
    const int*   src = ei;
    const int*   dst = ei + N_EDGES_;
    const float* W1  = (const float*)d_in[2];
    const float* b1  = (const float*)d_in[3];
    const float* W2  = (const float*)d_in[4];
    const float* b2  = (const float*)d_in[5];
    float* out = (float*)d_out;

    // workspace layout (256B aligned): h1 | agg1 | h2 | deg | dinv  (~104 MB)
    char* ws = (char*)d_ws;
    size_t off = 0;
    auto alloc = [&](size_t bytes) { void* p = ws + off; off = (off + bytes + 255) & ~(size_t)255; return p; };
    float* h1   = (float*)alloc((size_t)N_NODES_ * HIDDEN_ * 4);
    float* agg1 = (float*)alloc((size_t)N_NODES_ * HIDDEN_ * 4);
    float* h2   = (float*)alloc((size_t)N_NODES_ * N_CLASSES_ * 4);
    int*   deg  = (int*)alloc((size_t)N_NODES_ * 4);
    float* dinv = (float*)alloc((size_t)N_NODES_ * 4);

    hipMemsetAsync(deg, 0, (size_t)N_NODES_ * 4, stream);
    hipMemsetAsync(agg1, 0, (size_t)N_NODES_ * HIDDEN_ * 4, stream);
    hipMemsetAsync(out, 0, (size_t)N_NODES_ * N_CLASSES_ * 4, stream);

    deg_kernel<<<(N_EDGES_ + 255) / 256, 256, 0, stream>>>(dst, deg);
    dinv_kernel<<<(N_NODES_ + 255) / 256, 256, 0, stream>>>(deg, dinv);

    gemm1_kernel<<<dim3((N_NODES_ + TM - 1) / TM, HIDDEN_ / TN), 256, 0, stream>>>(x, W1, h1);

    long items = (long)N_EDGES_ + N_NODES_;
    long s1_threads = items * 64;
    scatter1_kernel<<<(unsigned)((s1_threads + 255) / 256), 256, 0, stream>>>(src, dst, dinv, h1, agg1);

    gemm2_kernel<<<(N_NODES_ + 3) / 4, 256, 0, stream>>>(agg1, b1, W2, h2);

    scatter2_kernel<<<(unsigned)((items + 255) / 256), 256, 0, stream>>>(src, dst, dinv, h2, out);

    bias2_kernel<<<(N_NODES_ * N_CLASSES_ + 255) / 256, 256, 0, stream>>>(out, b2);
}

// Round 2
// 1803.102 us; speedup vs baseline: 4.1129x; 4.1129x over previous
//
#include <hip/hip_runtime.h>
#include <hip/hip_bf16.h>

// GCN 2-layer forward.
// R1: replace atomic scatters with on-device CSR (bucket-by-dst) + register
// aggregation; fuse bias1+relu+GEMM2 into the aggregation epilogue; fuse
// scatter2+bias2 into a CSR-gather output kernel. Only int atomics remain
// (histogram + scatter cursors) -> deterministic f32 math, no 6.6 GB atomic
// write traffic.

#define N_NODES_   50000
#define N_EDGES_   1600000
#define N_FEAT_    1433
#define HIDDEN_    256
#define N_CLASSES_ 7

// ---------------- degree histogram ----------------
__global__ void deg_kernel(const int* __restrict__ dst, int* __restrict__ deg) {
    int i = blockIdx.x * blockDim.x + threadIdx.x;
    if (i < N_EDGES_) atomicAdd(&deg[dst[i]], 1);
}

__global__ void dinv_kernel(const int* __restrict__ deg, float* __restrict__ dinv) {
    int i = blockIdx.x * blockDim.x + threadIdx.x;
    if (i < N_NODES_) dinv[i] = rsqrtf((float)(deg[i] + 1));  // +1 self-loop
}

// ---------------- exclusive scan of deg -> row_ptr, cursor (single block) ----------------
#define SCAN_T 256
#define CHUNK_ ((N_NODES_ + SCAN_T - 1) / SCAN_T)  // 196
__global__ __launch_bounds__(SCAN_T) void scan_kernel(const int* __restrict__ deg,
                                                      int* __restrict__ row_ptr,
                                                      int* __restrict__ cursor) {
    __shared__ int sums[SCAN_T];
    int t = threadIdx.x;
    int lo = t * CHUNK_, hi = min(lo + CHUNK_, N_NODES_);
    int s = 0;
    for (int i = lo; i < hi; i++) s += deg[i];
    sums[t] = s;
    __syncthreads();
    for (int off = 1; off < SCAN_T; off <<= 1) {  // inclusive Hillis-Steele
        int v = (t >= off) ? sums[t - off] : 0;
        __syncthreads();
        sums[t] += v;
        __syncthreads();
    }
    int run = (t == 0) ? 0 : sums[t - 1];
    for (int i = lo; i < hi; i++) {
        row_ptr[i] = run;
        cursor[i]  = run;
        run += deg[i];
    }
    if (t == SCAN_T - 1) row_ptr[N_NODES_] = run;
}

// ---------------- bucket edges by dst ----------------
__global__ void csr_scatter_kernel(const int* __restrict__ src, const int* __restrict__ dst,
                                   int* __restrict__ cursor, int* __restrict__ csr_src) {
    int i = blockIdx.x * blockDim.x + threadIdx.x;
    if (i >= N_EDGES_) return;
    int d = dst[i];
    int pos = atomicAdd(&cursor[d], 1);
    csr_src[pos] = src[i];
}

// ---------------- GEMM1: h1 = x @ W1  (f32, 64x64 tile, 4x4 microtile) ----------------
#define TM 64
#define TN 64
#define TK 16
__global__ __launch_bounds__(256) void gemm1_kernel(const float* __restrict__ A,
                                                    const float* __restrict__ B,
                                                    float* __restrict__ C) {
    __shared__ float As[TK][TM + 4];
    __shared__ float Bs[TK][TN + 4];

    const int tid  = threadIdx.x;
    const int row0 = blockIdx.x * TM;
    const int col0 = blockIdx.y * TN;
    const int tr   = tid >> 4;
    const int tc   = tid & 15;

    float acc[4][4] = {};

    for (int k0 = 0; k0 < N_FEAT_; k0 += TK) {
        #pragma unroll
        for (int i = 0; i < 4; i++) {
            int idx = tid + i * 256;
            int m = idx >> 4;
            int k = idx & 15;
            int gm = row0 + m, gk = k0 + k;
            float v = 0.f;
            if (gm < N_NODES_ && gk < N_FEAT_) v = A[(long)gm * N_FEAT_ + gk];
            As[k][m] = v;
        }
        #pragma unroll
        for (int i = 0; i < 4; i++) {
            int idx = tid + i * 256;
            int k = idx >> 6;
            int n = idx & 63;
            int gk = k0 + k;
            float v = 0.f;
            if (gk < N_FEAT_) v = B[(long)gk * HIDDEN_ + col0 + n];
            Bs[k][n] = v;
        }
        __syncthreads();

        #pragma unroll
        for (int k = 0; k < TK; k++) {
            float4 a4 = *(const float4*)&As[k][tr * 4];
            float4 b4 = *(const float4*)&Bs[k][tc * 4];
            float a[4] = {a4.x, a4.y, a4.z, a4.w};
            float b[4] = {b4.x, b4.y, b4.z, b4.w};
            #pragma unroll
            for (int i = 0; i < 4; i++)
                #pragma unroll
                for (int j = 0; j < 4; j++)
                    acc[i][j] += a[i] * b[j];
        }
        __syncthreads();
    }

    #pragma unroll
    for (int i = 0; i < 4; i++) {
        int gm = row0 + tr * 4 + i;
        if (gm < N_NODES_) {
            float4 v = make_float4(acc[i][0], acc[i][1], acc[i][2], acc[i][3]);
            *(float4*)&C[(long)gm * HIDDEN_ + col0 + tc * 4] = v;
        }
    }
}

// ---------------- fused: agg1 (CSR gather) + bias1 + relu + GEMM2 ----------------
// One wave per dst node; lane holds features lane*4..lane*4+3.
__global__ __launch_bounds__(256) void agg_gemm2_kernel(const float* __restrict__ h1,
                                                        const int* __restrict__ row_ptr,
                                                        const int* __restrict__ csr_src,
                                                        const float* __restrict__ dinv,
                                                        const float* __restrict__ b1,
                                                        const float* __restrict__ W2,
                                                        float* __restrict__ h2) {
    __shared__ float w2s[HIDDEN_ * N_CLASSES_];
    __shared__ float b1s[HIDDEN_];
    int tid = threadIdx.x;
    for (int i = tid; i < HIDDEN_ * N_CLASSES_; i += 256) w2s[i] = W2[i];
    for (int i = tid; i < HIDDEN_; i += 256) b1s[i] = b1[i];
    __syncthreads();

    int wave = tid >> 6;
    int lane = tid & 63;
    int node = blockIdx.x * 4 + wave;
    if (node >= N_NODES_) return;

    int e0 = row_ptr[node], e1 = row_ptr[node + 1];
    float4 acc = make_float4(0.f, 0.f, 0.f, 0.f);
    for (int e = e0; e < e1; e++) {
        int s = csr_src[e];           // wave-uniform -> broadcast
        float ns = dinv[s];
        float4 v = ((const float4*)(h1 + (long)s * HIDDEN_))[lane];
        acc.x += v.x * ns;
        acc.y += v.y * ns;
        acc.z += v.z * ns;
        acc.w += v.w * ns;
    }
    float nd = dinv[node];
    float4 self = ((const float4*)(h1 + (long)node * HIDDEN_))[lane];
    float xv[4];
    xv[0] = fmaxf(acc.x * nd + self.x * nd * nd + b1s[lane * 4 + 0], 0.f);
    xv[1] = fmaxf(acc.y * nd + self.y * nd * nd + b1s[lane * 4 + 1], 0.f);
    xv[2] = fmaxf(acc.z * nd + self.z * nd * nd + b1s[lane * 4 + 2], 0.f);
    xv[3] = fmaxf(acc.w * nd + self.w * nd * nd + b1s[lane * 4 + 3], 0.f);

    float p[N_CLASSES_];
    #pragma unroll
    for (int c = 0; c < N_CLASSES_; c++) {
        float a = 0.f;
        #pragma unroll
        for (int i = 0; i < 4; i++)
            a += xv[i] * w2s[(lane * 4 + i) * N_CLASSES_ + c];
        p[c] = a;
    }
    #pragma unroll
    for (int off = 32; off > 0; off >>= 1)
        #pragma unroll
        for (int c = 0; c < N_CLASSES_; c++)
            p[c] += __shfl_down(p[c], off, 64);
    if (lane == 0) {
        #pragma unroll
        for (int c = 0; c < N_CLASSES_; c++)
            h2[(long)node * N_CLASSES_ + c] = p[c];
    }
}

// ---------------- output: CSR gather of h2 + self-loop + bias2 ----------------
// 8 lanes per node; lane c<7 accumulates class c.
__global__ void out_kernel(const float* __restrict__ h2,
                           const int* __restrict__ row_ptr,
                           const int* __restrict__ csr_src,
                           const float* __restrict__ dinv,
                           const float* __restrict__ b2,
                           float* __restrict__ out) {
    long gid = (long)blockIdx.x * blockDim.x + threadIdx.x;
    int node = (int)(gid >> 3);
    int c = (int)(gid & 7);
    if (node >= N_NODES_ || c >= N_CLASSES_) return;
    int e0 = row_ptr[node], e1 = row_ptr[node + 1];
    float acc = 0.f;
    for (int e = e0; e < e1; e++) {
        int s = csr_src[e];
        acc += h2[(long)s * N_CLASSES_ + c] * dinv[s];
    }
    float nd = dinv[node];
    out[(long)node * N_CLASSES_ + c] =
        acc * nd + h2[(long)node * N_CLASSES_ + c] * nd * nd + b2[c];
}

extern "C" void kernel_launch(void* const* d_in, const int* in_sizes, int n_in,
                              void* d_out, int out_size, void* d_ws, size_t ws_size,
                              hipStream_t stream) {
    const float* x   = (const float*)d_in[0];
    const int*   ei  = (const int*)d_in[1];
    const int*   src = ei;
    const int*   dst = ei + N_EDGES_;
    const float* W1  = (const float*)d_in[2];
    const float* b1  = (const float*)d_in[3];
    const float* W2  = (const float*)d_in[4];
    const float* b2  = (const float*)d_in[5];
    float* out = (float*)d_out;

    // workspace layout (256B aligned)
    char* ws = (char*)d_ws;
    size_t off = 0;
    auto alloc = [&](size_t bytes) { void* p = ws + off; off = (off + bytes + 255) & ~(size_t)255; return p; };
    float* h1      = (float*)alloc((size_t)N_NODES_ * HIDDEN_ * 4);     // 51.2 MB
    float* h2      = (float*)alloc((size_t)N_NODES_ * N_CLASSES_ * 4);  // 1.4 MB
    int*   deg     = (int*)alloc((size_t)N_NODES_ * 4);
    float* dinv    = (float*)alloc((size_t)N_NODES_ * 4);
    int*   row_ptr = (int*)alloc((size_t)(N_NODES_ + 1) * 4);
    int*   cursor  = (int*)alloc((size_t)N_NODES_ * 4);
    int*   csr_src = (int*)alloc((size_t)N_EDGES_ * 4);                 // 6.4 MB

    hipMemsetAsync(deg, 0, (size_t)N_NODES_ * 4, stream);

    deg_kernel<<<(N_EDGES_ + 255) / 256, 256, 0, stream>>>(dst, deg);
    dinv_kernel<<<(N_NODES_ + 255) / 256, 256, 0, stream>>>(deg, dinv);
    scan_kernel<<<1, SCAN_T, 0, stream>>>(deg, row_ptr, cursor);
    csr_scatter_kernel<<<(N_EDGES_ + 255) / 256, 256, 0, stream>>>(src, dst, cursor, csr_src);

    gemm1_kernel<<<dim3((N_NODES_ + TM - 1) / TM, HIDDEN_ / TN), 256, 0, stream>>>(x, W1, h1);

    agg_gemm2_kernel<<<(N_NODES_ + 3) / 4, 256, 0, stream>>>(h1, row_ptr, csr_src, dinv, b1, W2, h2);

    long out_threads = (long)N_NODES_ * 8;
    out_kernel<<<(unsigned)((out_threads + 255) / 256), 256, 0, stream>>>(h2, row_ptr, csr_src, dinv, b2, out);
}

// Round 3
// 1401.602 us; speedup vs baseline: 5.2910x; 1.2865x over previous
//
#include <hip/hip_runtime.h>
#include <hip/hip_bf16.h>

// GCN 2-layer forward.
// R1: CSR (bucket-by-dst) + deterministic register aggregation, fused
//     bias1+relu+GEMM2 and fused output gather.
// R2: GEMM1 on bf16 MFMA (16x16x32, 128x128 tile, BK=32). A-tile staged
//     f32->bf16 on the fly (x row pitch 1433 is odd -> scalar loads + pack);
//     B-tile = W1^T bf16 (padded K=1440) via global_load_lds 16B async.
//     h1 stored bf16 -> halves agg_gemm2 gather traffic.

#define N_NODES_   50000
#define N_EDGES_   1600000
#define N_FEAT_    1433
#define K_PAD_     1440
#define HIDDEN_    256
#define N_CLASSES_ 7

typedef __attribute__((ext_vector_type(8))) short short8;
typedef __attribute__((ext_vector_type(4))) float f32x4;
typedef unsigned int u32;
typedef unsigned short u16;

__device__ __forceinline__ u16 f2bf(float f) {
    __hip_bfloat16 h = __float2bfloat16(f);   // RNE
    return *(u16*)&h;
}
__device__ __forceinline__ u32 pack2bf(float a, float b) {
    return (u32)f2bf(a) | ((u32)f2bf(b) << 16);
}
__device__ __forceinline__ float bf2f(u16 u) {
    return __uint_as_float((u32)u << 16);
}
__device__ __forceinline__ void global_to_lds16(const void* g, void* l) {
    __builtin_amdgcn_global_load_lds(
        (const __attribute__((address_space(1))) u32*)g,
        (__attribute__((address_space(3))) u32*)l, 16, 0, 0);
}

// ---------------- degree histogram / norm ----------------
__global__ void deg_kernel(const int* __restrict__ dst, int* __restrict__ deg) {
    int i = blockIdx.x * blockDim.x + threadIdx.x;
    if (i < N_EDGES_) atomicAdd(&deg[dst[i]], 1);
}

__global__ void dinv_kernel(const int* __restrict__ deg, float* __restrict__ dinv) {
    int i = blockIdx.x * blockDim.x + threadIdx.x;
    if (i < N_NODES_) dinv[i] = rsqrtf((float)(deg[i] + 1));  // +1 self-loop
}

// ---------------- exclusive scan of deg -> row_ptr, cursor (single block) ----------------
#define SCAN_T 256
#define CHUNK_ ((N_NODES_ + SCAN_T - 1) / SCAN_T)
__global__ __launch_bounds__(SCAN_T) void scan_kernel(const int* __restrict__ deg,
                                                      int* __restrict__ row_ptr,
                                                      int* __restrict__ cursor) {
    __shared__ int sums[SCAN_T];
    int t = threadIdx.x;
    int lo = t * CHUNK_, hi = min(lo + CHUNK_, N_NODES_);
    int s = 0;
    for (int i = lo; i < hi; i++) s += deg[i];
    sums[t] = s;
    __syncthreads();
    for (int off = 1; off < SCAN_T; off <<= 1) {
        int v = (t >= off) ? sums[t - off] : 0;
        __syncthreads();
        sums[t] += v;
        __syncthreads();
    }
    int run = (t == 0) ? 0 : sums[t - 1];
    for (int i = lo; i < hi; i++) {
        row_ptr[i] = run;
        cursor[i]  = run;
        run += deg[i];
    }
    if (t == SCAN_T - 1) row_ptr[N_NODES_] = run;
}

// ---------------- bucket edges by dst ----------------
__global__ void csr_scatter_kernel(const int* __restrict__ src, const int* __restrict__ dst,
                                   int* __restrict__ cursor, int* __restrict__ csr_src) {
    int i = blockIdx.x * blockDim.x + threadIdx.x;
    if (i >= N_EDGES_) return;
    int d = dst[i];
    int pos = atomicAdd(&cursor[d], 1);
    csr_src[pos] = src[i];
}

// ---------------- W1 [1433][256] f32 -> W1T bf16 [256][1440] (zero-padded) ----------------
__global__ void w1t_kernel(const float* __restrict__ W1, u16* __restrict__ W1T) {
    int gid = blockIdx.x * blockDim.x + threadIdx.x;
    if (gid >= HIDDEN_ * K_PAD_) return;
    int k = gid % K_PAD_, n = gid / K_PAD_;
    float v = (k < N_FEAT_) ? W1[(long)k * HIDDEN_ + n] : 0.f;
    W1T[(long)n * K_PAD_ + k] = f2bf(v);
}

// ---------------- GEMM1 MFMA: h1b = bf16(x) @ bf16(W1) ----------------
#define BM 128
#define BN 128
#define BK 32
__global__ __launch_bounds__(256) void gemm1_mfma(const float* __restrict__ A,   // x [50000][1433] f32
                                                  const u16* __restrict__ BT,    // W1T [256][1440] bf16
                                                  u16* __restrict__ C) {         // h1b [50000][256] bf16
    __shared__ u16 As[BM * BK];  // [m][k], 64 B rows
    __shared__ u16 Bs[BN * BK];  // [n][k]

    const int tid  = threadIdx.x;
    const int lane = tid & 63;
    const int wv   = tid >> 6;
    const int row0 = blockIdx.x * BM;
    const int col0 = blockIdx.y * BN;
    const int wr0  = (wv >> 1) * 64;
    const int wc0  = (wv & 1) * 64;

    f32x4 acc[4][4] = {};

    const int tr = tid >> 4;          // 0..15
    const int tk = (tid & 15) * 2;    // k-pair within BK

    for (int k0 = 0; k0 < N_FEAT_; k0 += BK) {
        // A stage: 8 groups of 16 rows; f32 scalar loads -> bf16 pack -> ds_write_b32
        #pragma unroll
        for (int i = 0; i < 8; i++) {
            int m  = i * 16 + tr;
            int gm = row0 + m; if (gm > N_NODES_ - 1) gm = N_NODES_ - 1;  // clamp, discarded in epilogue
            int gk = k0 + tk;
            const float* ap = A + (long)gm * N_FEAT_ + gk;
            float f0 = (gk     < N_FEAT_) ? ap[0] : 0.f;
            float f1 = (gk + 1 < N_FEAT_) ? ap[1] : 0.f;
            *(u32*)&As[m * BK + tk] = pack2bf(f0, f1);
        }
        // B stage: async 16B direct-to-LDS, 2 issues (lane -> n=(l>>2), k-quad=(l&3)*8)
        {
            int n  = lane >> 2;
            int kq = (lane & 3) * 8;
            #pragma unroll
            for (int j = 0; j < 2; j++) {
                int nt = j * 64 + wv * 16 + n;  // 0..127
                const u16* g = BT + (long)(col0 + nt) * K_PAD_ + k0 + kq;
                u16* l = &Bs[(j * 64 + wv * 16) * BK] + lane * 8;  // lane*16 bytes from wave base
                global_to_lds16(g, l);
            }
        }
        __syncthreads();

        const int fm = lane & 15;
        const int fq = (lane >> 4) * 8;
        short8 af[4], bf[4];
        #pragma unroll
        for (int mi = 0; mi < 4; mi++)
            af[mi] = *(const short8*)&As[(wr0 + mi * 16 + fm) * BK + fq];
        #pragma unroll
        for (int ni = 0; ni < 4; ni++)
            bf[ni] = *(const short8*)&Bs[(wc0 + ni * 16 + fm) * BK + fq];
        #pragma unroll
        for (int mi = 0; mi < 4; mi++)
            #pragma unroll
            for (int ni = 0; ni < 4; ni++)
                acc[mi][ni] = __builtin_amdgcn_mfma_f32_16x16x32_bf16(af[mi], bf[ni], acc[mi][ni], 0, 0, 0);
        __syncthreads();
    }

    // epilogue: C/D layout col=lane&15, row=(lane>>4)*4+r
    const int fm = lane & 15;
    const int q4 = (lane >> 4) * 4;
    #pragma unroll
    for (int mi = 0; mi < 4; mi++) {
        #pragma unroll
        for (int r = 0; r < 4; r++) {
            int gm = row0 + wr0 + mi * 16 + q4 + r;
            if (gm < N_NODES_) {
                #pragma unroll
                for (int ni = 0; ni < 4; ni++) {
                    int gn = col0 + wc0 + ni * 16 + fm;
                    C[(long)gm * HIDDEN_ + gn] = f2bf(acc[mi][ni][r]);
                }
            }
        }
    }
}

// ---------------- fused: agg1 (CSR gather of bf16 h1) + bias1 + relu + GEMM2 ----------------
__global__ __launch_bounds__(256) void agg_gemm2_kernel(const u16* __restrict__ h1b,
                                                        const int* __restrict__ row_ptr,
                                                        const int* __restrict__ csr_src,
                                                        const float* __restrict__ dinv,
                                                        const float* __restrict__ b1,
                                                        const float* __restrict__ W2,
                                                        float* __restrict__ h2) {
    __shared__ float w2s[HIDDEN_ * N_CLASSES_];
    __shared__ float b1s[HIDDEN_];
    int tid = threadIdx.x;
    for (int i = tid; i < HIDDEN_ * N_CLASSES_; i += 256) w2s[i] = W2[i];
    for (int i = tid; i < HIDDEN_; i += 256) b1s[i] = b1[i];
    __syncthreads();

    int wave = tid >> 6;
    int lane = tid & 63;
    int node = blockIdx.x * 4 + wave;
    if (node >= N_NODES_) return;

    int e0 = row_ptr[node], e1 = row_ptr[node + 1];
    float ax = 0.f, ay = 0.f, az = 0.f, aw = 0.f;
    for (int e = e0; e < e1; e++) {
        int s = csr_src[e];                    // wave-uniform -> broadcast
        float ns = dinv[s];
        ushort4 u = ((const ushort4*)(h1b + (long)s * HIDDEN_))[lane];
        ax += bf2f(u.x) * ns;
        ay += bf2f(u.y) * ns;
        az += bf2f(u.z) * ns;
        aw += bf2f(u.w) * ns;
    }
    float nd = dinv[node];
    ushort4 su = ((const ushort4*)(h1b + (long)node * HIDDEN_))[lane];
    float xv[4];
    xv[0] = fmaxf(ax * nd + bf2f(su.x) * nd * nd + b1s[lane * 4 + 0], 0.f);
    xv[1] = fmaxf(ay * nd + bf2f(su.y) * nd * nd + b1s[lane * 4 + 1], 0.f);
    xv[2] = fmaxf(az * nd + bf2f(su.z) * nd * nd + b1s[lane * 4 + 2], 0.f);
    xv[3] = fmaxf(aw * nd + bf2f(su.w) * nd * nd + b1s[lane * 4 + 3], 0.f);

    float p[N_CLASSES_];
    #pragma unroll
    for (int c = 0; c < N_CLASSES_; c++) {
        float a = 0.f;
        #pragma unroll
        for (int i = 0; i < 4; i++)
            a += xv[i] * w2s[(lane * 4 + i) * N_CLASSES_ + c];
        p[c] = a;
    }
    #pragma unroll
    for (int off = 32; off > 0; off >>= 1)
        #pragma unroll
        for (int c = 0; c < N_CLASSES_; c++)
            p[c] += __shfl_down(p[c], off, 64);
    if (lane == 0) {
        #pragma unroll
        for (int c = 0; c < N_CLASSES_; c++)
            h2[(long)node * N_CLASSES_ + c] = p[c];
    }
}

// ---------------- output: CSR gather of h2 + self-loop + bias2 ----------------
__global__ void out_kernel(const float* __restrict__ h2,
                           const int* __restrict__ row_ptr,
                           const int* __restrict__ csr_src,
                           const float* __restrict__ dinv,
                           const float* __restrict__ b2,
                           float* __restrict__ out) {
    long gid = (long)blockIdx.x * blockDim.x + threadIdx.x;
    int node = (int)(gid >> 3);
    int c = (int)(gid & 7);
    if (node >= N_NODES_ || c >= N_CLASSES_) return;
    int e0 = row_ptr[node], e1 = row_ptr[node + 1];
    float acc = 0.f;
    for (int e = e0; e < e1; e++) {
        int s = csr_src[e];
        acc += h2[(long)s * N_CLASSES_ + c] * dinv[s];
    }
    float nd = dinv[node];
    out[(long)node * N_CLASSES_ + c] =
        acc * nd + h2[(long)node * N_CLASSES_ + c] * nd * nd + b2[c];
}

extern "C" void kernel_launch(void* const* d_in, const int* in_sizes, int n_in,
                              void* d_out, int out_size, void* d_ws, size_t ws_size,
                              hipStream_t stream) {
    const float* x   = (const float*)d_in[0];
    const int*   ei  = (const int*)d_in[1];
    const int*   src = ei;
    const int*   dst = ei + N_EDGES_;
    const float* W1  = (const float*)d_in[2];
    const float* b1  = (const float*)d_in[3];
    const float* W2  = (const float*)d_in[4];
    const float* b2  = (const float*)d_in[5];
    float* out = (float*)d_out;

    // workspace layout (256B aligned), ~36 MB total
    char* ws = (char*)d_ws;
    size_t off = 0;
    auto alloc = [&](size_t bytes) { void* p = ws + off; off = (off + bytes + 255) & ~(size_t)255; return p; };
    u16*   h1b     = (u16*)alloc((size_t)N_NODES_ * HIDDEN_ * 2);     // 25.6 MB
    u16*   w1t     = (u16*)alloc((size_t)HIDDEN_ * K_PAD_ * 2);       // 0.74 MB
    float* h2      = (float*)alloc((size_t)N_NODES_ * N_CLASSES_ * 4);
    int*   deg     = (int*)alloc((size_t)N_NODES_ * 4);
    float* dinv    = (float*)alloc((size_t)N_NODES_ * 4);
    int*   row_ptr = (int*)alloc((size_t)(N_NODES_ + 1) * 4);
    int*   cursor  = (int*)alloc((size_t)N_NODES_ * 4);
    int*   csr_src = (int*)alloc((size_t)N_EDGES_ * 4);               // 6.4 MB

    hipMemsetAsync(deg, 0, (size_t)N_NODES_ * 4, stream);

    deg_kernel<<<(N_EDGES_ + 255) / 256, 256, 0, stream>>>(dst, deg);
    dinv_kernel<<<(N_NODES_ + 255) / 256, 256, 0, stream>>>(deg, dinv);
    scan_kernel<<<1, SCAN_T, 0, stream>>>(deg, row_ptr, cursor);
    csr_scatter_kernel<<<(N_EDGES_ + 255) / 256, 256, 0, stream>>>(src, dst, cursor, csr_src);

    w1t_kernel<<<(HIDDEN_ * K_PAD_ + 255) / 256, 256, 0, stream>>>(W1, w1t);

    gemm1_mfma<<<dim3((N_NODES_ + BM - 1) / BM, HIDDEN_ / BN), 256, 0, stream>>>(x, w1t, h1b);

    agg_gemm2_kernel<<<(N_NODES_ + 3) / 4, 256, 0, stream>>>(h1b, row_ptr, csr_src, dinv, b1, W2, h2);

    long out_threads = (long)N_NODES_ * 8;
    out_kernel<<<(unsigned)((out_threads + 255) / 256), 256, 0, stream>>>(h2, row_ptr, csr_src, dinv, b2, out);
}

// Round 4
// 964.333 us; speedup vs baseline: 7.6902x; 1.4534x over previous
//
#include <hip/hip_runtime.h>
#include <hip/hip_bf16.h>

// GCN 2-layer forward.
// R1: CSR (bucket-by-dst) + deterministic register aggregation; fused
//     bias1+relu+GEMM2; fused output gather.
// R2: GEMM1 on bf16 MFMA.
// R3: pre-convert x->bf16 padded (xb[50048][1440]) so GEMM1 is pure m97
//     structure (global_load_lds 16B for BOTH operands, no VALU repack —
//     R2's fused f32->bf16 staging serialized 8x900cyc loads/iter);
//     agg_gemm2: wave-batched edge-index loads + shfl broadcast + 4-way
//     unrolled row gathers for MLP.

#define N_NODES_   50000
#define NB_ROWS_   50048   // N_NODES_ rounded up to BM
#define N_EDGES_   1600000
#define N_FEAT_    1433
#define K_PAD_     1440
#define HIDDEN_    256
#define N_CLASSES_ 7

typedef __attribute__((ext_vector_type(8))) short short8;
typedef __attribute__((ext_vector_type(4))) float f32x4;
typedef unsigned int u32;
typedef unsigned short u16;

__device__ __forceinline__ u16 f2bf(float f) {
    __hip_bfloat16 h = __float2bfloat16(f);   // RNE
    return *(u16*)&h;
}
__device__ __forceinline__ float bf2f(u16 u) {
    return __uint_as_float((u32)u << 16);
}
__device__ __forceinline__ void global_to_lds16(const void* g, void* l) {
    __builtin_amdgcn_global_load_lds(
        (const __attribute__((address_space(1))) u32*)g,
        (__attribute__((address_space(3))) u32*)l, 16, 0, 0);
}

// ---------------- degree histogram / norm ----------------
__global__ void deg_kernel(const int* __restrict__ dst, int* __restrict__ deg) {
    int i = blockIdx.x * blockDim.x + threadIdx.x;
    if (i < N_EDGES_) atomicAdd(&deg[dst[i]], 1);
}

__global__ void dinv_kernel(const int* __restrict__ deg, float* __restrict__ dinv) {
    int i = blockIdx.x * blockDim.x + threadIdx.x;
    if (i < N_NODES_) dinv[i] = rsqrtf((float)(deg[i] + 1));  // +1 self-loop
}

// ---------------- exclusive scan of deg -> row_ptr, cursor (single block) ----------------
#define SCAN_T 256
#define CHUNK_ ((N_NODES_ + SCAN_T - 1) / SCAN_T)
__global__ __launch_bounds__(SCAN_T) void scan_kernel(const int* __restrict__ deg,
                                                      int* __restrict__ row_ptr,
                                                      int* __restrict__ cursor) {
    __shared__ int sums[SCAN_T];
    int t = threadIdx.x;
    int lo = t * CHUNK_, hi = min(lo + CHUNK_, N_NODES_);
    int s = 0;
    for (int i = lo; i < hi; i++) s += deg[i];
    sums[t] = s;
    __syncthreads();
    for (int off = 1; off < SCAN_T; off <<= 1) {
        int v = (t >= off) ? sums[t - off] : 0;
        __syncthreads();
        sums[t] += v;
        __syncthreads();
    }
    int run = (t == 0) ? 0 : sums[t - 1];
    for (int i = lo; i < hi; i++) {
        row_ptr[i] = run;
        cursor[i]  = run;
        run += deg[i];
    }
    if (t == SCAN_T - 1) row_ptr[N_NODES_] = run;
}

// ---------------- bucket edges by dst ----------------
__global__ void csr_scatter_kernel(const int* __restrict__ src, const int* __restrict__ dst,
                                   int* __restrict__ cursor, int* __restrict__ csr_src) {
    int i = blockIdx.x * blockDim.x + threadIdx.x;
    if (i >= N_EDGES_) return;
    int d = dst[i];
    int pos = atomicAdd(&cursor[d], 1);
    csr_src[pos] = src[i];
}

// ---------------- x [50000][1433] f32 -> xb [50048][1440] bf16 (zero pad) ----------------
__global__ __launch_bounds__(256) void cvt_kernel(const float* __restrict__ x,
                                                  u16* __restrict__ xb) {
    int row = blockIdx.x;
    int t = threadIdx.x;
    const float* xr = x + (long)row * N_FEAT_;
    u16* xbr = xb + (long)row * K_PAD_;
    bool valid = row < N_NODES_;
    for (int k = t; k < K_PAD_; k += 256) {
        float v = (valid && k < N_FEAT_) ? xr[k] : 0.f;
        xbr[k] = f2bf(v);
    }
}

// ---------------- W1 [1433][256] f32 -> W1T bf16 [256][1440] (zero-padded) ----------------
__global__ void w1t_kernel(const float* __restrict__ W1, u16* __restrict__ W1T) {
    int gid = blockIdx.x * blockDim.x + threadIdx.x;
    if (gid >= HIDDEN_ * K_PAD_) return;
    int k = gid % K_PAD_, n = gid / K_PAD_;
    float v = (k < N_FEAT_) ? W1[(long)k * HIDDEN_ + n] : 0.f;
    W1T[(long)n * K_PAD_ + k] = f2bf(v);
}

// ---------------- GEMM1 MFMA: h1b = xb @ W1  (m97 structure) ----------------
#define BM 128
#define BN 128
#define BK 32
__global__ __launch_bounds__(256) void gemm1_mfma(const u16* __restrict__ A,    // xb [50048][1440] bf16
                                                  const u16* __restrict__ BT,   // W1T [256][1440] bf16
                                                  u16* __restrict__ C) {        // h1b [50000][256] bf16
    __shared__ u16 As[BM * BK];  // [m][k], 64 B rows, 8 KB
    __shared__ u16 Bs[BN * BK];  // [n][k], 8 KB

    const int tid  = threadIdx.x;
    const int lane = tid & 63;
    const int wv   = tid >> 6;
    const int row0 = blockIdx.x * BM;
    const int col0 = blockIdx.y * BN;
    const int wr0  = (wv >> 1) * 64;
    const int wc0  = (wv & 1) * 64;

    f32x4 acc[4][4] = {};

    // staging map: lane i -> row (base + i>>2), k-offset (i&3)*8 (16 B per lane)
    const int srow = lane >> 2;
    const int skk  = (lane & 3) * 8;

    for (int k0 = 0; k0 < K_PAD_; k0 += BK) {
        // A: wave wv stages rows [wv*32, wv*32+32), 2 issues of 16 rows
        #pragma unroll
        for (int j = 0; j < 2; j++) {
            int rbase = wv * 32 + j * 16;
            const u16* g = A + (long)(row0 + rbase + srow) * K_PAD_ + k0 + skk;
            global_to_lds16(g, &As[rbase * BK]);
        }
        // B: wave wv stages rows {wv*16 .. wv*16+15} and {64+wv*16 ..}
        #pragma unroll
        for (int j = 0; j < 2; j++) {
            int rbase = j * 64 + wv * 16;
            const u16* g = BT + (long)(col0 + rbase + srow) * K_PAD_ + k0 + skk;
            global_to_lds16(g, &Bs[rbase * BK]);
        }
        __syncthreads();

        const int fm = lane & 15;
        const int fq = (lane >> 4) * 8;
        short8 af[4], bf[4];
        #pragma unroll
        for (int mi = 0; mi < 4; mi++)
            af[mi] = *(const short8*)&As[(wr0 + mi * 16 + fm) * BK + fq];
        #pragma unroll
        for (int ni = 0; ni < 4; ni++)
            bf[ni] = *(const short8*)&Bs[(wc0 + ni * 16 + fm) * BK + fq];
        #pragma unroll
        for (int mi = 0; mi < 4; mi++)
            #pragma unroll
            for (int ni = 0; ni < 4; ni++)
                acc[mi][ni] = __builtin_amdgcn_mfma_f32_16x16x32_bf16(af[mi], bf[ni], acc[mi][ni], 0, 0, 0);
        __syncthreads();
    }

    // epilogue: C/D layout col=lane&15, row=(lane>>4)*4+r
    const int fm = lane & 15;
    const int q4 = (lane >> 4) * 4;
    #pragma unroll
    for (int mi = 0; mi < 4; mi++) {
        #pragma unroll
        for (int r = 0; r < 4; r++) {
            int gm = row0 + wr0 + mi * 16 + q4 + r;
            if (gm < N_NODES_) {
                #pragma unroll
                for (int ni = 0; ni < 4; ni++) {
                    int gn = col0 + wc0 + ni * 16 + fm;
                    C[(long)gm * HIDDEN_ + gn] = f2bf(acc[mi][ni][r]);
                }
            }
        }
    }
}

// ---------------- fused: agg1 (CSR gather of bf16 h1) + bias1 + relu + GEMM2 ----------------
// One wave per dst node. Edge indices+norms batch-loaded 64 at a time
// (coalesced), shfl-broadcast; row gathers unrolled x4 for MLP.
__global__ __launch_bounds__(256) void agg_gemm2_kernel(const u16* __restrict__ h1b,
                                                        const int* __restrict__ row_ptr,
                                                        const int* __restrict__ csr_src,
                                                        const float* __restrict__ dinv,
                                                        const float* __restrict__ b1,
                                                        const float* __restrict__ W2,
                                                        float* __restrict__ h2) {
    __shared__ float w2s[HIDDEN_ * N_CLASSES_];
    __shared__ float b1s[HIDDEN_];
    int tid = threadIdx.x;
    for (int i = tid; i < HIDDEN_ * N_CLASSES_; i += 256) w2s[i] = W2[i];
    for (int i = tid; i < HIDDEN_; i += 256) b1s[i] = b1[i];
    __syncthreads();

    int wave = tid >> 6;
    int lane = tid & 63;
    int node = blockIdx.x * 4 + wave;
    if (node >= N_NODES_) return;

    int e0 = row_ptr[node], e1 = row_ptr[node + 1];
    float ax = 0.f, ay = 0.f, az = 0.f, aw = 0.f;
    for (int base = e0; base < e1; base += 64) {
        int myE = base + lane;
        int sL = 0;
        float nsL = 0.f;
        if (myE < e1) {
            sL = csr_src[myE];
            nsL = dinv[sL];
        }
        int cnt4 = (min(64, e1 - base) + 3) & ~3;
        for (int j = 0; j < cnt4; j += 4) {
            #pragma unroll
            for (int t = 0; t < 4; t++) {
                int s   = __shfl(sL, j + t, 64);
                float ns = __shfl(nsL, j + t, 64);
                ushort4 u = ((const ushort4*)(h1b + (long)s * HIDDEN_))[lane];
                ax += bf2f(u.x) * ns;
                ay += bf2f(u.y) * ns;
                az += bf2f(u.z) * ns;
                aw += bf2f(u.w) * ns;
            }
        }
    }
    float nd = dinv[node];
    ushort4 su = ((const ushort4*)(h1b + (long)node * HIDDEN_))[lane];
    float xv[4];
    xv[0] = fmaxf(ax * nd + bf2f(su.x) * nd * nd + b1s[lane * 4 + 0], 0.f);
    xv[1] = fmaxf(ay * nd + bf2f(su.y) * nd * nd + b1s[lane * 4 + 1], 0.f);
    xv[2] = fmaxf(az * nd + bf2f(su.z) * nd * nd + b1s[lane * 4 + 2], 0.f);
    xv[3] = fmaxf(aw * nd + bf2f(su.w) * nd * nd + b1s[lane * 4 + 3], 0.f);

    float p[N_CLASSES_];
    #pragma unroll
    for (int c = 0; c < N_CLASSES_; c++) {
        float a = 0.f;
        #pragma unroll
        for (int i = 0; i < 4; i++)
            a += xv[i] * w2s[(lane * 4 + i) * N_CLASSES_ + c];
        p[c] = a;
    }
    #pragma unroll
    for (int off = 32; off > 0; off >>= 1)
        #pragma unroll
        for (int c = 0; c < N_CLASSES_; c++)
            p[c] += __shfl_down(p[c], off, 64);
    if (lane == 0) {
        #pragma unroll
        for (int c = 0; c < N_CLASSES_; c++)
            h2[(long)node * N_CLASSES_ + c] = p[c];
    }
}

// ---------------- output: CSR gather of h2 + self-loop + bias2 ----------------
__global__ void out_kernel(const float* __restrict__ h2,
                           const int* __restrict__ row_ptr,
                           const int* __restrict__ csr_src,
                           const float* __restrict__ dinv,
                           const float* __restrict__ b2,
                           float* __restrict__ out) {
    long gid = (long)blockIdx.x * blockDim.x + threadIdx.x;
    int node = (int)(gid >> 3);
    int c = (int)(gid & 7);
    if (node >= N_NODES_ || c >= N_CLASSES_) return;
    int e0 = row_ptr[node], e1 = row_ptr[node + 1];
    float acc = 0.f;
    for (int e = e0; e < e1; e++) {
        int s = csr_src[e];
        acc += h2[(long)s * N_CLASSES_ + c] * dinv[s];
    }
    float nd = dinv[node];
    out[(long)node * N_CLASSES_ + c] =
        acc * nd + h2[(long)node * N_CLASSES_ + c] * nd * nd + b2[c];
}

extern "C" void kernel_launch(void* const* d_in, const int* in_sizes, int n_in,
                              void* d_out, int out_size, void* d_ws, size_t ws_size,
                              hipStream_t stream) {
    const float* x   = (const float*)d_in[0];
    const int*   ei  = (const int*)d_in[1];
    const int*   src = ei;
    const int*   dst = ei + N_EDGES_;
    const float* W1  = (const float*)d_in[2];
    const float* b1  = (const float*)d_in[3];
    const float* W2  = (const float*)d_in[4];
    const float* b2  = (const float*)d_in[5];
    float* out = (float*)d_out;

    // workspace layout (256B aligned), ~179 MB total
    char* ws = (char*)d_ws;
    size_t off = 0;
    auto alloc = [&](size_t bytes) { void* p = ws + off; off = (off + bytes + 255) & ~(size_t)255; return p; };
    u16*   xb      = (u16*)alloc((size_t)NB_ROWS_ * K_PAD_ * 2);      // 144.1 MB
    u16*   h1b     = (u16*)alloc((size_t)N_NODES_ * HIDDEN_ * 2);     // 25.6 MB
    u16*   w1t     = (u16*)alloc((size_t)HIDDEN_ * K_PAD_ * 2);       // 0.74 MB
    float* h2      = (float*)alloc((size_t)N_NODES_ * N_CLASSES_ * 4);
    int*   deg     = (int*)alloc((size_t)N_NODES_ * 4);
    float* dinv    = (float*)alloc((size_t)N_NODES_ * 4);
    int*   row_ptr = (int*)alloc((size_t)(N_NODES_ + 1) * 4);
    int*   cursor  = (int*)alloc((size_t)N_NODES_ * 4);
    int*   csr_src = (int*)alloc((size_t)N_EDGES_ * 4);               // 6.4 MB

    hipMemsetAsync(deg, 0, (size_t)N_NODES_ * 4, stream);

    deg_kernel<<<(N_EDGES_ + 255) / 256, 256, 0, stream>>>(dst, deg);
    dinv_kernel<<<(N_NODES_ + 255) / 256, 256, 0, stream>>>(deg, dinv);
    scan_kernel<<<1, SCAN_T, 0, stream>>>(deg, row_ptr, cursor);
    csr_scatter_kernel<<<(N_EDGES_ + 255) / 256, 256, 0, stream>>>(src, dst, cursor, csr_src);

    cvt_kernel<<<NB_ROWS_, 256, 0, stream>>>(x, xb);
    w1t_kernel<<<(HIDDEN_ * K_PAD_ + 255) / 256, 256, 0, stream>>>(W1, w1t);

    gemm1_mfma<<<dim3(NB_ROWS_ / BM, HIDDEN_ / BN), 256, 0, stream>>>(xb, w1t, h1b);

    agg_gemm2_kernel<<<(N_NODES_ + 3) / 4, 256, 0, stream>>>(h1b, row_ptr, csr_src, dinv, b1, W2, h2);

    long out_threads = (long)N_NODES_ * 8;
    out_kernel<<<(unsigned)((out_threads + 255) / 256), 256, 0, stream>>>(h2, row_ptr, csr_src, dinv, b2, out);
}

// Round 5
// 893.833 us; speedup vs baseline: 8.2968x; 1.0789x over previous
//
#include <hip/hip_runtime.h>
#include <hip/hip_bf16.h>

// GCN 2-layer forward.
// R1: CSR + deterministic register aggregation; fused bias1+relu+GEMM2; fused output.
// R2: GEMM1 on bf16 MFMA (16x16x32, 128x128 tile).
// R3: pre-converted bf16 operands; m97-style global_load_lds staging both tiles.
// R4: parallel 3-phase scan (was single-block); vectorized cvt (ushort8 stores);
//     h1/h2 pre-scaled by dinv[src] in producer epilogues (deletes per-edge
//     dinv gather+mul); branch-free gather loops via zeroed pad row; deeper
//     software pipelining (prefetch next index batch, 8 gathers in flight).

#define N_NODES_   50000
#define NB_ROWS_   50048   // N_NODES_ rounded up to BM
#define N_EDGES_   1600000
#define N_FEAT_    1433
#define K_PAD_     1440
#define HIDDEN_    256
#define N_CLASSES_ 7
#define NPART_     ((N_NODES_ + 255) / 256)   // 196 scan partials

typedef __attribute__((ext_vector_type(8))) short short8;
typedef __attribute__((ext_vector_type(8))) unsigned short ushort8;
typedef __attribute__((ext_vector_type(4))) float f32x4;
typedef unsigned int u32;
typedef unsigned short u16;

__device__ __forceinline__ u16 f2bf(float f) {
    __hip_bfloat16 h = __float2bfloat16(f);   // RNE
    return *(u16*)&h;
}
__device__ __forceinline__ float bf2f(u16 u) {
    return __uint_as_float((u32)u << 16);
}
__device__ __forceinline__ void global_to_lds16(const void* g, void* l) {
    __builtin_amdgcn_global_load_lds(
        (const __attribute__((address_space(1))) u32*)g,
        (__attribute__((address_space(3))) u32*)l, 16, 0, 0);
}

// ---------------- degree histogram / norm ----------------
__global__ void deg_kernel(const int* __restrict__ dst, int* __restrict__ deg) {
    int i = blockIdx.x * blockDim.x + threadIdx.x;
    if (i < N_EDGES_) atomicAdd(&deg[dst[i]], 1);
}

__global__ void dinv_kernel(const int* __restrict__ deg, float* __restrict__ dinv) {
    int i = blockIdx.x * blockDim.x + threadIdx.x;
    if (i < N_NODES_) dinv[i] = rsqrtf((float)(deg[i] + 1));  // +1 self-loop
}

// ---------------- parallel scan: deg -> row_ptr/cursor ----------------
// s1: per-block (256-elem) partial sums
__global__ __launch_bounds__(256) void scan1_kernel(const int* __restrict__ deg,
                                                    int* __restrict__ partial) {
    __shared__ int ws[4];
    int t = threadIdx.x, b = blockIdx.x;
    int idx = b * 256 + t;
    int v = (idx < N_NODES_) ? deg[idx] : 0;
    #pragma unroll
    for (int off = 32; off > 0; off >>= 1) v += __shfl_down(v, off, 64);
    if ((t & 63) == 0) ws[t >> 6] = v;
    __syncthreads();
    if (t == 0) partial[b] = ws[0] + ws[1] + ws[2] + ws[3];
}

// s2: exclusive scan of NPART_ partials (single block)
__global__ __launch_bounds__(256) void scan2_kernel(int* __restrict__ partial,
                                                    int* __restrict__ blk_off) {
    __shared__ int sh[256];
    int t = threadIdx.x;
    int v = (t < NPART_) ? partial[t] : 0;
    sh[t] = v;
    __syncthreads();
    #pragma unroll
    for (int off = 1; off < 256; off <<= 1) {
        int a = (t >= off) ? sh[t - off] : 0;
        __syncthreads();
        sh[t] += a;
        __syncthreads();
    }
    if (t < NPART_) blk_off[t] = sh[t] - v;  // exclusive
}

// s3: in-block exclusive scan + add block offset -> row_ptr, cursor
__global__ __launch_bounds__(256) void scan3_kernel(const int* __restrict__ deg,
                                                    const int* __restrict__ blk_off,
                                                    int* __restrict__ row_ptr,
                                                    int* __restrict__ cursor) {
    __shared__ int sh[256];
    int t = threadIdx.x, b = blockIdx.x;
    int idx = b * 256 + t;
    int v = (idx < N_NODES_) ? deg[idx] : 0;
    sh[t] = v;
    __syncthreads();
    #pragma unroll
    for (int off = 1; off < 256; off <<= 1) {
        int a = (t >= off) ? sh[t - off] : 0;
        __syncthreads();
        sh[t] += a;
        __syncthreads();
    }
    if (idx < N_NODES_) {
        int rp = blk_off[b] + sh[t] - v;
        row_ptr[idx] = rp;
        cursor[idx]  = rp;
    }
    if (idx == 0) row_ptr[N_NODES_] = N_EDGES_;
}

// ---------------- bucket edges by dst ----------------
__global__ void csr_scatter_kernel(const int* __restrict__ src, const int* __restrict__ dst,
                                   int* __restrict__ cursor, int* __restrict__ csr_src) {
    int i = blockIdx.x * blockDim.x + threadIdx.x;
    if (i >= N_EDGES_) return;
    int d = dst[i];
    int pos = atomicAdd(&cursor[d], 1);
    csr_src[pos] = src[i];
}

// ---------------- x [50000][1433] f32 -> xb [50048][1440] bf16 (zero pad) ----------------
// One row per 192-thread block; lane k-range [t*8, t*8+8), one 16B store.
__global__ __launch_bounds__(192) void cvt_kernel(const float* __restrict__ x,
                                                  u16* __restrict__ xb) {
    int row = blockIdx.x;
    int t = threadIdx.x;
    if (t >= K_PAD_ / 8) return;
    int k0 = t * 8;
    const float* xr = x + (long)row * N_FEAT_;
    bool vrow = row < N_NODES_;
    ushort8 o;
    #pragma unroll
    for (int j = 0; j < 8; j++) {
        int k = k0 + j;
        float v = (vrow && k < N_FEAT_) ? xr[k] : 0.f;
        o[j] = f2bf(v);
    }
    *(ushort8*)(xb + (long)row * K_PAD_ + k0) = o;
}

// ---------------- W1 [1433][256] f32 -> W1T bf16 [256][1440] (zero-padded) ----------------
__global__ void w1t_kernel(const float* __restrict__ W1, u16* __restrict__ W1T) {
    int gid = blockIdx.x * blockDim.x + threadIdx.x;
    if (gid >= HIDDEN_ * K_PAD_) return;
    int k = gid % K_PAD_, n = gid / K_PAD_;
    float v = (k < N_FEAT_) ? W1[(long)k * HIDDEN_ + n] : 0.f;
    W1T[(long)n * K_PAD_ + k] = f2bf(v);
}

// ---------------- GEMM1 MFMA: h1s = (xb @ W1) * dinv[row]  (m97 structure) ----------------
#define BM 128
#define BN 128
#define BK 32
__global__ __launch_bounds__(256) void gemm1_mfma(const u16* __restrict__ A,    // xb [50048][1440] bf16
                                                  const u16* __restrict__ BT,   // W1T [256][1440] bf16
                                                  const float* __restrict__ dinv,
                                                  u16* __restrict__ C) {        // h1s [50001][256] bf16
    __shared__ u16 As[BM * BK];  // [m][k], 64 B rows, 8 KB
    __shared__ u16 Bs[BN * BK];  // [n][k], 8 KB

    const int tid  = threadIdx.x;
    const int lane = tid & 63;
    const int wv   = tid >> 6;
    const int row0 = blockIdx.x * BM;
    const int col0 = blockIdx.y * BN;
    const int wr0  = (wv >> 1) * 64;
    const int wc0  = (wv & 1) * 64;

    f32x4 acc[4][4] = {};

    const int srow = lane >> 2;
    const int skk  = (lane & 3) * 8;

    for (int k0 = 0; k0 < K_PAD_; k0 += BK) {
        #pragma unroll
        for (int j = 0; j < 2; j++) {
            int rbase = wv * 32 + j * 16;
            const u16* g = A + (long)(row0 + rbase + srow) * K_PAD_ + k0 + skk;
            global_to_lds16(g, &As[rbase * BK]);
        }
        #pragma unroll
        for (int j = 0; j < 2; j++) {
            int rbase = j * 64 + wv * 16;
            const u16* g = BT + (long)(col0 + rbase + srow) * K_PAD_ + k0 + skk;
            global_to_lds16(g, &Bs[rbase * BK]);
        }
        __syncthreads();

        const int fm = lane & 15;
        const int fq = (lane >> 4) * 8;
        short8 af[4], bf[4];
        #pragma unroll
        for (int mi = 0; mi < 4; mi++)
            af[mi] = *(const short8*)&As[(wr0 + mi * 16 + fm) * BK + fq];
        #pragma unroll
        for (int ni = 0; ni < 4; ni++)
            bf[ni] = *(const short8*)&Bs[(wc0 + ni * 16 + fm) * BK + fq];
        #pragma unroll
        for (int mi = 0; mi < 4; mi++)
            #pragma unroll
            for (int ni = 0; ni < 4; ni++)
                acc[mi][ni] = __builtin_amdgcn_mfma_f32_16x16x32_bf16(af[mi], bf[ni], acc[mi][ni], 0, 0, 0);
        __syncthreads();
    }

    // epilogue: C/D layout col=lane&15, row=(lane>>4)*4+r; scale by dinv[row]
    const int fm = lane & 15;
    const int q4 = (lane >> 4) * 4;
    #pragma unroll
    for (int mi = 0; mi < 4; mi++) {
        #pragma unroll
        for (int r = 0; r < 4; r++) {
            int gm = row0 + wr0 + mi * 16 + q4 + r;
            if (gm < N_NODES_) {
                float sc = dinv[gm];
                #pragma unroll
                for (int ni = 0; ni < 4; ni++) {
                    int gn = col0 + wc0 + ni * 16 + fm;
                    C[(long)gm * HIDDEN_ + gn] = f2bf(acc[mi][ni][r] * sc);
                }
            }
        }
    }
}

// ---------------- fused: agg1 (row-sum of pre-scaled h1s) + bias1 + relu + GEMM2 ----------------
// One wave per dst node; branch-free inner loop (pad lanes -> zero row N_NODES_);
// next index batch prefetched; 8 row-gathers in flight.
__global__ __launch_bounds__(256) void agg_gemm2_kernel(const u16* __restrict__ h1s,
                                                        const int* __restrict__ row_ptr,
                                                        const int* __restrict__ csr_src,
                                                        const float* __restrict__ dinv,
                                                        const float* __restrict__ b1,
                                                        const float* __restrict__ W2,
                                                        float* __restrict__ h2s) {
    __shared__ float w2s[HIDDEN_ * N_CLASSES_];
    __shared__ float b1s[HIDDEN_];
    int tid = threadIdx.x;
    for (int i = tid; i < HIDDEN_ * N_CLASSES_; i += 256) w2s[i] = W2[i];
    for (int i = tid; i < HIDDEN_; i += 256) b1s[i] = b1[i];
    __syncthreads();

    int wave = tid >> 6;
    int lane = tid & 63;
    int node = blockIdx.x * 4 + wave;
    if (node >= N_NODES_) return;

    int e0 = row_ptr[node], e1 = row_ptr[node + 1];
    float ax = 0.f, ay = 0.f, az = 0.f, aw = 0.f;

    int sL = (e0 + lane < e1) ? csr_src[e0 + lane] : N_NODES_;
    for (int base = e0; base < e1; base += 64) {
        int sCur = sL;
        int nb = base + 64;
        if (nb < e1) sL = (nb + lane < e1) ? csr_src[nb + lane] : N_NODES_;
        int cnt8 = (min(64, e1 - base) + 7) & ~7;
        for (int j = 0; j < cnt8; j += 8) {
            #pragma unroll
            for (int t = 0; t < 8; t++) {
                int s = __shfl(sCur, j + t, 64);
                ushort4 u = ((const ushort4*)(h1s + (long)s * HIDDEN_))[lane];
                ax += bf2f(u.x);
                ay += bf2f(u.y);
                az += bf2f(u.z);
                aw += bf2f(u.w);
            }
        }
    }
    float nd = dinv[node];
    ushort4 su = ((const ushort4*)(h1s + (long)node * HIDDEN_))[lane];
    float xv[4];
    xv[0] = fmaxf((ax + bf2f(su.x)) * nd + b1s[lane * 4 + 0], 0.f);
    xv[1] = fmaxf((ay + bf2f(su.y)) * nd + b1s[lane * 4 + 1], 0.f);
    xv[2] = fmaxf((az + bf2f(su.z)) * nd + b1s[lane * 4 + 2], 0.f);
    xv[3] = fmaxf((aw + bf2f(su.w)) * nd + b1s[lane * 4 + 3], 0.f);

    float p[N_CLASSES_];
    #pragma unroll
    for (int c = 0; c < N_CLASSES_; c++) {
        float a = 0.f;
        #pragma unroll
        for (int i = 0; i < 4; i++)
            a += xv[i] * w2s[(lane * 4 + i) * N_CLASSES_ + c];
        p[c] = a;
    }
    #pragma unroll
    for (int off = 32; off > 0; off >>= 1)
        #pragma unroll
        for (int c = 0; c < N_CLASSES_; c++)
            p[c] += __shfl_down(p[c], off, 64);
    if (lane == 0) {
        #pragma unroll
        for (int c = 0; c < N_CLASSES_; c++)
            h2s[(long)node * 8 + c] = p[c] * nd;   // pre-scaled, stride-8 rows
    }
}

// ---------------- output: row-sum of pre-scaled h2s + self + bias2 ----------------
// 8 lanes per node (lane 7 idle); 4 gathers in flight.
__global__ void out_kernel(const float* __restrict__ h2s,
                           const int* __restrict__ row_ptr,
                           const int* __restrict__ csr_src,
                           const float* __restrict__ dinv,
                           const float* __restrict__ b2,
                           float* __restrict__ out) {
    long gid = (long)blockIdx.x * blockDim.x + threadIdx.x;
    int node = (int)(gid >> 3);
    int c = (int)(gid & 7);
    if (node >= N_NODES_ || c >= N_CLASSES_) return;
    int e0 = row_ptr[node], e1 = row_ptr[node + 1];
    float acc = 0.f;
    for (int e = e0; e < e1; e += 4) {
        int s0 = csr_src[e];
        int s1 = (e + 1 < e1) ? csr_src[e + 1] : N_NODES_;
        int s2 = (e + 2 < e1) ? csr_src[e + 2] : N_NODES_;
        int s3 = (e + 3 < e1) ? csr_src[e + 3] : N_NODES_;
        float v0 = h2s[(long)s0 * 8 + c];
        float v1 = h2s[(long)s1 * 8 + c];
        float v2 = h2s[(long)s2 * 8 + c];
        float v3 = h2s[(long)s3 * 8 + c];
        acc += (v0 + v1) + (v2 + v3);
    }
    float nd = dinv[node];
    out[(long)node * N_CLASSES_ + c] =
        (acc + h2s[(long)node * 8 + c]) * nd + b2[c];
}

extern "C" void kernel_launch(void* const* d_in, const int* in_sizes, int n_in,
                              void* d_out, int out_size, void* d_ws, size_t ws_size,
                              hipStream_t stream) {
    const float* x   = (const float*)d_in[0];
    const int*   ei  = (const int*)d_in[1];
    const int*   src = ei;
    const int*   dst = ei + N_EDGES_;
    const float* W1  = (const float*)d_in[2];
    const float* b1  = (const float*)d_in[3];
    const float* W2  = (const float*)d_in[4];
    const float* b2  = (const float*)d_in[5];
    float* out = (float*)d_out;

    // workspace layout (256B aligned), ~179 MB total
    char* ws = (char*)d_ws;
    size_t off = 0;
    auto alloc = [&](size_t bytes) { void* p = ws + off; off = (off + bytes + 255) & ~(size_t)255; return p; };
    u16*   xb      = (u16*)alloc((size_t)NB_ROWS_ * K_PAD_ * 2);          // 144.1 MB
    u16*   h1s     = (u16*)alloc((size_t)(N_NODES_ + 1) * HIDDEN_ * 2);   // 25.6 MB (+pad row)
    u16*   w1t     = (u16*)alloc((size_t)HIDDEN_ * K_PAD_ * 2);           // 0.74 MB
    float* h2s     = (float*)alloc((size_t)(N_NODES_ + 1) * 8 * 4);       // 1.6 MB (+pad row)
    int*   deg     = (int*)alloc((size_t)N_NODES_ * 4);
    float* dinv    = (float*)alloc((size_t)N_NODES_ * 4);
    int*   row_ptr = (int*)alloc((size_t)(N_NODES_ + 1) * 4);
    int*   cursor  = (int*)alloc((size_t)N_NODES_ * 4);
    int*   csr_src = (int*)alloc((size_t)N_EDGES_ * 4);                   // 6.4 MB
    int*   partial = (int*)alloc((size_t)NPART_ * 4);
    int*   blk_off = (int*)alloc((size_t)NPART_ * 4);

    hipMemsetAsync(deg, 0, (size_t)N_NODES_ * 4, stream);
    hipMemsetAsync(h1s + (size_t)N_NODES_ * HIDDEN_, 0, HIDDEN_ * 2, stream);  // zero pad row
    hipMemsetAsync(h2s + (size_t)N_NODES_ * 8, 0, 8 * 4, stream);              // zero pad row

    deg_kernel<<<(N_EDGES_ + 255) / 256, 256, 0, stream>>>(dst, deg);
    dinv_kernel<<<(N_NODES_ + 255) / 256, 256, 0, stream>>>(deg, dinv);
    scan1_kernel<<<NPART_, 256, 0, stream>>>(deg, partial);
    scan2_kernel<<<1, 256, 0, stream>>>(partial, blk_off);
    scan3_kernel<<<NPART_, 256, 0, stream>>>(deg, blk_off, row_ptr, cursor);
    csr_scatter_kernel<<<(N_EDGES_ + 255) / 256, 256, 0, stream>>>(src, dst, cursor, csr_src);

    cvt_kernel<<<NB_ROWS_, 192, 0, stream>>>(x, xb);
    w1t_kernel<<<(HIDDEN_ * K_PAD_ + 255) / 256, 256, 0, stream>>>(W1, w1t);

    gemm1_mfma<<<dim3(NB_ROWS_ / BM, HIDDEN_ / BN), 256, 0, stream>>>(xb, w1t, dinv, h1s);

    agg_gemm2_kernel<<<(N_NODES_ + 3) / 4, 256, 0, stream>>>(h1s, row_ptr, csr_src, dinv, b1, W2, h2s);

    long out_threads = (long)N_NODES_ * 8;
    out_kernel<<<(unsigned)((out_threads + 255) / 256), 256, 0, stream>>>(h2s, row_ptr, csr_src, dinv, b2, out);
}